// Round 13
// baseline (92.018 us; speedup 1.0000x reference)
//
#include <hip/hip_runtime.h>

// PrRoIPool2D forward, MI355X. B=8, C=256, H=W=48, R=300, 7x7 bins, scale=1/16.
// R13: ROI-pair software pipelining on the R10/R11 structure (fp32).
// Block = (channel-octet, roi-pair). Schedule:
//   A: write patch(r0); issue r1 global loads -> regs   | bar
//   B: PA(r0)                                           | bar
//   C: PB(r0) stores + write patch(r1) from regs        | bar
//   D: PA(r1)                                           | bar
//   E: PB(r1)
// r1's global latency hidden behind r0 compute; prologue amortized over 2 rois;
// 4800 blocks; LDS 25.8 KB -> 6 blocks/CU (same as R10).

#define PH 7
#define PW 7
#define NBINS 49
#define SCALE 0.0625f
#define CH 256
#define FH 48
#define FW 48
#define RNUM 300
#define CB 8                 // channels per block
#define MAXJ 23              // max patch rows
#define ROWF 28              // max patch row width (floats)
#define PRM 128              // param stride per roi (floats) -> 512 B
// layout per roi (floats):
//  [ph*8+0..5]  wy[ph] (pre-scaled by inv_area)   [ph*8+6] bj bits  [+7] pad
//  [56+pw*8+0..5] wx[pw]                          [..+6]  bi bits   [+7] pad
//  [112] b bits  [113] J0 bits  [114] I0 bits  [115] (JROWS | NI4<<8) bits

__device__ __forceinline__ float hat_int(float x, float g) {
    float t = x - (g - 1.0f);
    if (t <= 0.0f) return 0.0f;
    if (t <= 1.0f) return 0.5f * t * t;
    if (t <= 2.0f) { float u = 2.0f - t; return 1.0f - 0.5f * u * u; }
    return 1.0f;
}

// ---- prep: per-roi windows/weights/bounds, once (unchanged from R11) ----
__global__ __launch_bounds__(256)
void prroi_prep(const float* __restrict__ rois, float* __restrict__ prm) {
    const int r = blockIdx.x * 4 + (threadIdx.x >> 6);
    const int t = threadIdx.x & 63;
    if (r >= RNUM || t >= 15) return;

    const float* roi = rois + r * 5;
    const int   b  = (int)roi[0];
    const float x1 = roi[1] * SCALE, y1 = roi[2] * SCALE;
    const float x2 = roi[3] * SCALE, y2 = roi[4] * SCALE;
    const float roi_w = fmaxf(x2 - x1, 0.0f), roi_h = fmaxf(y2 - y1, 0.0f);
    const float bin_w = roi_w / (float)PW, bin_h = roi_h / (float)PH;
    const float area = bin_w * bin_h;
    const float inv_area = (area > 0.0f) ? (1.0f / area) : 0.0f;

    const float ylo = fminf(y1, y2), yhi = fmaxf(y1, y2);
    const float xlo = fminf(x1, x2), xhi = fmaxf(x1, x2);
    const int j1 = min(FH - 1, (int)floorf(yhi) + 1);
    const int i1 = min(FW - 1, (int)floorf(xhi) + 1);
    const int J0 = min(max(0, (int)floorf(ylo) - 1), FH - 6);
    const int I0 = min(max(0, (int)floorf(xlo) - 1) & ~3, FW - 8);
    const int JROWS = min(FH - J0, max(j1 - J0 + 1, 6));        // 6..23
    int NI4 = min(((i1 - I0) >> 2) + 1, (FW - I0) >> 2);
    NI4 = max(NI4, 2);                                           // 2..7

    float* p = prm + (size_t)r * PRM;
    if (t < PH) {
        const int ph = t;
        const float ya = y1 + ph * bin_h, yb = ya + bin_h;
        const int base = min(max((int)floorf(ya) - 1, J0), J0 + JROWS - 6);
#pragma unroll
        for (int k = 0; k < 6; ++k) {
            const float g = (float)(base + k);
            p[ph * 8 + k] = (hat_int(yb, g) - hat_int(ya, g)) * inv_area;
        }
        p[ph * 8 + 6] = __int_as_float(base - J0);
        p[ph * 8 + 7] = 0.0f;
    } else if (t < PH + PW) {
        const int pw = t - PH;
        const float xa = x1 + pw * bin_w, xb = xa + bin_w;
        const int base = min(max((int)floorf(xa) - 1, I0), I0 + 4 * NI4 - 6);
#pragma unroll
        for (int k = 0; k < 6; ++k) {
            const float g = (float)(base + k);
            p[56 + pw * 8 + k] = hat_int(xb, g) - hat_int(xa, g);
        }
        p[56 + pw * 8 + 6] = __int_as_float(base - I0);
        p[56 + pw * 8 + 7] = 0.0f;
    } else {                                                     // t == 14
        p[112] = __int_as_float(b);
        p[113] = __int_as_float(J0);
        p[114] = __int_as_float(I0);
        p[115] = __int_as_float(JROWS | (NI4 << 8));
    }
}

// ---- PA / PB helpers (operate on LDS patch / rs with register weights) ----
__device__ __forceinline__ void do_PA(const float* __restrict__ patch,
                                      float* __restrict__ rs,
                                      int jA, int qA, int pwA, int biA, int JROWS,
                                      const float4& wxv0, const float4& wxv1) {
    if (pwA < PW) {
        const float* base0 = &patch[((size_t)jA * ROWF + biA) * CB + 4 * qA];
        float* rdst = &rs[((size_t)pwA * MAXJ + jA) * CB + 4 * qA];
        for (int j = jA; j < JROWS; j += 16) {
            float ax, ay, az, aw;
            {
                const float4 v = *(const float4*)(base0 + 0 * CB);
                ax = wxv0.x * v.x; ay = wxv0.x * v.y; az = wxv0.x * v.z; aw = wxv0.x * v.w;
            }
            {
                const float4 v = *(const float4*)(base0 + 1 * CB);
                ax += wxv0.y * v.x; ay += wxv0.y * v.y; az += wxv0.y * v.z; aw += wxv0.y * v.w;
            }
            {
                const float4 v = *(const float4*)(base0 + 2 * CB);
                ax += wxv0.z * v.x; ay += wxv0.z * v.y; az += wxv0.z * v.z; aw += wxv0.z * v.w;
            }
            {
                const float4 v = *(const float4*)(base0 + 3 * CB);
                ax += wxv0.w * v.x; ay += wxv0.w * v.y; az += wxv0.w * v.z; aw += wxv0.w * v.w;
            }
            {
                const float4 v = *(const float4*)(base0 + 4 * CB);
                ax += wxv1.x * v.x; ay += wxv1.x * v.y; az += wxv1.x * v.z; aw += wxv1.x * v.w;
            }
            {
                const float4 v = *(const float4*)(base0 + 5 * CB);
                ax += wxv1.y * v.x; ay += wxv1.y * v.y; az += wxv1.y * v.z; aw += wxv1.y * v.w;
            }
            *(float4*)rdst = make_float4(ax, ay, az, aw);
            base0 += (size_t)16 * ROWF * CB;
            rdst  += 16 * CB;
        }
    }
}

__device__ __forceinline__ void do_PB(const float* __restrict__ rs,
                                      float* __restrict__ out,
                                      int r, int c0, int bin, int cp, int pwv, int bj,
                                      const float4& wyv0, const float4& wyv1) {
    if (bin < NBINS) {
        const float* rbase = &rs[((size_t)pwv * MAXJ + bj) * CB + 2 * cp];
        float ax = 0.0f, ay = 0.0f;
        { const float2 v = *(const float2*)(rbase + 0 * CB); ax += wyv0.x * v.x; ay += wyv0.x * v.y; }
        { const float2 v = *(const float2*)(rbase + 1 * CB); ax += wyv0.y * v.x; ay += wyv0.y * v.y; }
        { const float2 v = *(const float2*)(rbase + 2 * CB); ax += wyv0.z * v.x; ay += wyv0.z * v.y; }
        { const float2 v = *(const float2*)(rbase + 3 * CB); ax += wyv0.w * v.x; ay += wyv0.w * v.y; }
        { const float2 v = *(const float2*)(rbase + 4 * CB); ax += wyv1.x * v.x; ay += wyv1.x * v.y; }
        { const float2 v = *(const float2*)(rbase + 5 * CB); ax += wyv1.y * v.x; ay += wyv1.y * v.y; }
        float* o = out + ((size_t)r * CH + c0 + 2 * cp) * NBINS + bin;
        o[0]     = ax;
        o[NBINS] = ay;
    }
}

// ---- main: roi-pair pipelined ----
__global__ __launch_bounds__(256)
void prroi_main(const float* __restrict__ feat,
                const float* __restrict__ prm,
                float* __restrict__ out) {
    const int cblk = blockIdx.x;        // 0..31
    const int r0   = 2 * blockIdx.y;    // 0..298
    const int r1   = r0 + 1;
    const int c0   = cblk * CB;
    const int tid  = threadIdx.x;

    __shared__ float patch[MAXJ * ROWF * CB];   // [j][i][c8] 20608 B (reused r0->r1)
    __shared__ float rs[PW * MAXJ * CB];        // [pw][j][c8]  5152 B (reused)

    const float* p0 = prm + (size_t)r0 * PRM;
    const float* p1 = prm + (size_t)r1 * PRM;

    // ---- prefetch params for BOTH rois (10 float4 loads) ----
    const float4 misc0 = *(const float4*)(p0 + 112);
    const float4 misc1 = *(const float4*)(p1 + 112);
    const int qA  = tid & 1;
    const int pwA = (tid >> 1) & 7;             // 7 -> idle lane
    const int jA  = tid >> 4;                   // 0..15
    const float4 wx0v0 = *(const float4*)(p0 + 56 + pwA * 8);
    const float4 wx0v1 = *(const float4*)(p0 + 56 + pwA * 8 + 4);
    const float4 wx1v0 = *(const float4*)(p1 + 56 + pwA * 8);
    const float4 wx1v1 = *(const float4*)(p1 + 56 + pwA * 8 + 4);
    const int bin = tid & 63;
    const int cp  = tid >> 6;
    const int phv = bin / 7;
    const int pwv = bin - phv * 7;
    const float4 wy0v0 = *(const float4*)(p0 + phv * 8);
    const float4 wy0v1 = *(const float4*)(p0 + phv * 8 + 4);
    const float4 wy1v0 = *(const float4*)(p1 + phv * 8);
    const float4 wy1v1 = *(const float4*)(p1 + phv * 8 + 4);

    const int b0 = __float_as_int(misc0.x), J00 = __float_as_int(misc0.y);
    const int I00 = __float_as_int(misc0.z);
    const int pk0 = __float_as_int(misc0.w);
    const int JROWS0 = pk0 & 255, NI40 = pk0 >> 8;
    const int b1 = __float_as_int(misc1.x), J01 = __float_as_int(misc1.y);
    const int I01 = __float_as_int(misc1.z);
    const int pk1 = __float_as_int(misc1.w);
    const int JROWS1 = pk1 & 255, NI41 = pk1 >> 8;
    const int biA0 = __float_as_int(wx0v1.z), bj0 = __float_as_int(wy0v1.z);
    const int biA1 = __float_as_int(wx1v1.z), bj1 = __float_as_int(wy1v1.z);

    // ---- P1 mapping ----
    const int i4P = tid & 7;
    const int qP  = (tid >> 3) & 1;
    const int jbP = tid >> 4;                   // 0..15

    // ---- Phase A: write patch(r0); then issue r1 first-slot loads -> regs ----
    if (i4P < NI40) {
        const float* src = feat + (size_t)(b0 * CH + c0 + 4 * qP) * FH * FW
                         + (size_t)(J00 + jbP) * FW + I00 + 4 * i4P;
        float* dst = &patch[((size_t)jbP * ROWF + 4 * i4P) * CB + 4 * qP];
        for (int j = jbP; j < JROWS0; j += 16) {
            const float4 v0 = *(const float4*)(src);
            const float4 v1 = *(const float4*)(src + FH * FW);
            const float4 v2 = *(const float4*)(src + 2 * FH * FW);
            const float4 v3 = *(const float4*)(src + 3 * FH * FW);
            *(float4*)(dst + 0 * CB) = make_float4(v0.x, v1.x, v2.x, v3.x);
            *(float4*)(dst + 1 * CB) = make_float4(v0.y, v1.y, v2.y, v3.y);
            *(float4*)(dst + 2 * CB) = make_float4(v0.z, v1.z, v2.z, v3.z);
            *(float4*)(dst + 3 * CB) = make_float4(v0.w, v1.w, v2.w, v3.w);
            src += 16 * FW;
            dst += (size_t)16 * ROWF * CB;
        }
    }
    // issue r1 loads for first j-slot now (latency hidden behind B/C)
    float4 u0, u1, u2, u3;
    const bool have1 = (i4P < NI41) && (jbP < JROWS1);
    const float* src1 = feat + (size_t)(b1 * CH + c0 + 4 * qP) * FH * FW
                      + (size_t)(J01 + jbP) * FW + I01 + 4 * i4P;
    if (have1) {
        u0 = *(const float4*)(src1);
        u1 = *(const float4*)(src1 + FH * FW);
        u2 = *(const float4*)(src1 + 2 * FH * FW);
        u3 = *(const float4*)(src1 + 3 * FH * FW);
    }
    __syncthreads();

    // ---- Phase B: PA(r0) ----
    do_PA(patch, rs, jA, qA, pwA, biA0, JROWS0, wx0v0, wx0v1);
    __syncthreads();

    // ---- Phase C: PB(r0) stores + write patch(r1) ----
    do_PB(rs, out, r0, c0, bin, cp, pwv, bj0, wy0v0, wy0v1);
    if (have1) {
        float* dst = &patch[((size_t)jbP * ROWF + 4 * i4P) * CB + 4 * qP];
        *(float4*)(dst + 0 * CB) = make_float4(u0.x, u1.x, u2.x, u3.x);
        *(float4*)(dst + 1 * CB) = make_float4(u0.y, u1.y, u2.y, u3.y);
        *(float4*)(dst + 2 * CB) = make_float4(u0.z, u1.z, u2.z, u3.z);
        *(float4*)(dst + 3 * CB) = make_float4(u0.w, u1.w, u2.w, u3.w);
        // rare tail (JROWS1 > 16): load + write directly
        if (jbP + 16 < JROWS1) {
            const float* s2 = src1 + 16 * FW;
            const float4 w0 = *(const float4*)(s2);
            const float4 w1 = *(const float4*)(s2 + FH * FW);
            const float4 w2 = *(const float4*)(s2 + 2 * FH * FW);
            const float4 w3 = *(const float4*)(s2 + 3 * FH * FW);
            float* d2 = dst + (size_t)16 * ROWF * CB;
            *(float4*)(d2 + 0 * CB) = make_float4(w0.x, w1.x, w2.x, w3.x);
            *(float4*)(d2 + 1 * CB) = make_float4(w0.y, w1.y, w2.y, w3.y);
            *(float4*)(d2 + 2 * CB) = make_float4(w0.z, w1.z, w2.z, w3.z);
            *(float4*)(d2 + 3 * CB) = make_float4(w0.w, w1.w, w2.w, w3.w);
        }
    }
    __syncthreads();

    // ---- Phase D: PA(r1) ----
    do_PA(patch, rs, jA, qA, pwA, biA1, JROWS1, wx1v0, wx1v1);
    __syncthreads();

    // ---- Phase E: PB(r1) ----
    do_PB(rs, out, r1, c0, bin, cp, pwv, bj1, wy1v0, wy1v1);
}

extern "C" void kernel_launch(void* const* d_in, const int* in_sizes, int n_in,
                              void* d_out, int out_size, void* d_ws, size_t ws_size,
                              hipStream_t stream) {
    const float* feat = (const float*)d_in[0];
    const float* rois = (const float*)d_in[1];
    float* out = (float*)d_out;
    float* prm = (float*)d_ws;   // 300 * 128 * 4 = 153.6 KB

    prroi_prep<<<(RNUM + 3) / 4, 256, 0, stream>>>(rois, prm);
    prroi_main<<<dim3(CH / CB, RNUM / 2), 256, 0, stream>>>(feat, prm, out);
}

// Round 14
// 89.181 us; speedup vs baseline: 1.0318x; 1.0318x over previous
//
#include <hip/hip_runtime.h>

// PrRoIPool2D forward, MI355X. B=8, C=256, H=W=48, R=300, 7x7 bins, scale=1/16.
// R14 = R10 resubmitted verbatim (best measured config: 87.8 us).
// Structure: prep kernel hoists all per-ROI math into a 448 B/roi table in
// d_ws; main kernel prefetches params into registers before the first barrier
// (latency hidden behind P1 staging), then P1 stage patch [j][i][c8] ->
// PA row-sums rs[pw][j][c8] -> PB combine. LDS 25.8 KB -> 6 blocks/CU.
//
// Plateau note (R8-R13): occupancy 2x, bank-conflict de-striding, issue-count
// cuts, bf16 LDS, and ROI-pair pipelining all landed 88-95 us. Kernel portion
// ~30 us = ~14 LDS + ~10 VALU + ~5 global issue, phase-serialized; harness
// fill/restore floor ~58.6 us dominates total.

#define PH 7
#define PW 7
#define NBINS 49
#define SCALE 0.0625f
#define CH 256
#define FH 48
#define FW 48
#define RNUM 300
#define CB 8                 // channels per block
#define MAXJ 23              // max patch rows
#define ROWF 28              // max patch row width (floats)
#define PRM 112              // param stride per roi (floats)
// param layout: [0+ph*6]: wy[7][6] | [42+pw*6]: wx[7][6] | [84+ph]: bj (int)
// [91+pw]: bi (int) | [98]: inv_area | [99]: b | [100]: J0 | [101]: I0
// [102]: JROWS | [103]: NI4   (ints stored as float bit patterns)

__device__ __forceinline__ float hat_int(float x, float g) {
    float t = x - (g - 1.0f);
    if (t <= 0.0f) return 0.0f;
    if (t <= 1.0f) return 0.5f * t * t;
    if (t <= 2.0f) { float u = 2.0f - t; return 1.0f - 0.5f * u * u; }
    return 1.0f;
}

// ---- prep: per-roi windows/weights/bounds, once ----
__global__ __launch_bounds__(256)
void prroi_prep(const float* __restrict__ rois, float* __restrict__ prm) {
    const int r = blockIdx.x * 4 + (threadIdx.x >> 6);
    const int t = threadIdx.x & 63;
    if (r >= RNUM || t >= 15) return;

    const float* roi = rois + r * 5;
    const int   b  = (int)roi[0];
    const float x1 = roi[1] * SCALE, y1 = roi[2] * SCALE;
    const float x2 = roi[3] * SCALE, y2 = roi[4] * SCALE;
    const float roi_w = fmaxf(x2 - x1, 0.0f), roi_h = fmaxf(y2 - y1, 0.0f);
    const float bin_w = roi_w / (float)PW, bin_h = roi_h / (float)PH;
    const float area = bin_w * bin_h;
    const float inv_area = (area > 0.0f) ? (1.0f / area) : 0.0f;

    const float ylo = fminf(y1, y2), yhi = fmaxf(y1, y2);
    const float xlo = fminf(x1, x2), xhi = fmaxf(x1, x2);
    const int j1 = min(FH - 1, (int)floorf(yhi) + 1);
    const int i1 = min(FW - 1, (int)floorf(xhi) + 1);
    const int J0 = min(max(0, (int)floorf(ylo) - 1), FH - 6);
    const int I0 = min(max(0, (int)floorf(xlo) - 1) & ~3, FW - 8);
    const int JROWS = min(FH - J0, max(j1 - J0 + 1, 6));        // 6..23
    int NI4 = min(((i1 - I0) >> 2) + 1, (FW - I0) >> 2);
    NI4 = max(NI4, 2);                                           // 2..7

    float* p = prm + (size_t)r * PRM;
    if (t < PH) {
        const int ph = t;
        const float ya = y1 + ph * bin_h, yb = ya + bin_h;
        const int base = min(max((int)floorf(ya) - 1, J0), J0 + JROWS - 6);
        p[84 + ph] = __int_as_float(base - J0);
#pragma unroll
        for (int k = 0; k < 6; ++k) {
            const float g = (float)(base + k);
            p[ph * 6 + k] = hat_int(yb, g) - hat_int(ya, g);    // 0 outside support
        }
    } else if (t < PH + PW) {
        const int pw = t - PH;
        const float xa = x1 + pw * bin_w, xb = xa + bin_w;
        const int base = min(max((int)floorf(xa) - 1, I0), I0 + 4 * NI4 - 6);
        p[91 + pw] = __int_as_float(base - I0);
#pragma unroll
        for (int k = 0; k < 6; ++k) {
            const float g = (float)(base + k);
            p[42 + pw * 6 + k] = hat_int(xb, g) - hat_int(xa, g);
        }
    } else {                                                     // t == 14
        p[98]  = inv_area;
        p[99]  = __int_as_float(b);
        p[100] = __int_as_float(J0);
        p[101] = __int_as_float(I0);
        p[102] = __int_as_float(JROWS);
        p[103] = __int_as_float(NI4);
    }
}

// ---- main ----
__global__ __launch_bounds__(256)
void prroi_main(const float* __restrict__ feat,
                const float* __restrict__ prm,
                float* __restrict__ out) {
    const int cblk = blockIdx.x;        // 0..31
    const int r    = blockIdx.y;        // 0..299
    const int c0   = cblk * CB;
    const int tid  = threadIdx.x;

    __shared__ float patch[MAXJ * ROWF * CB];   // [j][i][c8] 20608 B
    __shared__ float rs[PW * MAXJ * CB];        // [pw][j][c8]  5152 B

    const float* p = prm + (size_t)r * PRM;
    const int b     = __float_as_int(p[99]);
    const int J0    = __float_as_int(p[100]);
    const int I0    = __float_as_int(p[101]);
    const int JROWS = __float_as_int(p[102]);
    const int NI4   = __float_as_int(p[103]);

    // ---- prefetch PA params (units v1 = tid, v2 = tid + 256) ----
    const int nA = JROWS * 14;
    const int v1 = tid, v2 = tid + 256;
    int pw1 = 0, q1 = 0, j1r = 0, pw2 = 0, q2 = 0, j2r = 0, bi1 = 0, bi2 = 0;
    float wxa[6], wxb[6];
    const bool a1 = v1 < nA, a2 = v2 < nA;
    if (a1) {
        j1r = v1 / 14; const int rem = v1 - j1r * 14; pw1 = rem >> 1; q1 = rem & 1;
        bi1 = __float_as_int(p[91 + pw1]);
#pragma unroll
        for (int k = 0; k < 6; ++k) wxa[k] = p[42 + pw1 * 6 + k];
    }
    if (a2) {
        j2r = v2 / 14; const int rem = v2 - j2r * 14; pw2 = rem >> 1; q2 = rem & 1;
        bi2 = __float_as_int(p[91 + pw2]);
#pragma unroll
        for (int k = 0; k < 6; ++k) wxb[k] = p[42 + pw2 * 6 + k];
    }

    // ---- prefetch PB params ----
    const int bin = tid & 63;
    const int cp  = tid >> 6;
    float wy[6]; int bj = 0, phv = 0, pwv = 0;
    float inv_area = p[98];
    if (bin < NBINS) {
        phv = bin / PW; pwv = bin - phv * PW;
        bj = __float_as_int(p[84 + phv]);
#pragma unroll
        for (int k = 0; k < 6; ++k) wy[k] = p[phv * 6 + k];
    }

    // ---- P1: stage patch rectangle, channel-fast, 4x4 register transpose ----
    const float* fb = feat + (size_t)(b * CH + c0) * FH * FW;
    for (int u = tid; u < 2 * MAXJ * 7; u += 256) {    // 322 units
        const int q   = u / (MAXJ * 7);                // channel quad 0..1
        const int rem = u - q * (MAXJ * 7);
        const int j   = rem / 7;
        const int i4  = rem - j * 7;
        if (j < JROWS && i4 < NI4) {
            const int ig = I0 + 4 * i4;                // <= FW-4 by construction
            const float* src = fb + ((size_t)(4 * q) * FH + (J0 + j)) * FW + ig;
            const float4 v0 = *(const float4*)(src);
            const float4 v1v = *(const float4*)(src + FH * FW);
            const float4 v2v = *(const float4*)(src + 2 * FH * FW);
            const float4 v3v = *(const float4*)(src + 3 * FH * FW);
            float* dst = &patch[((size_t)j * ROWF + 4 * i4) * CB + 4 * q];
            *(float4*)(dst + 0 * CB) = make_float4(v0.x, v1v.x, v2v.x, v3v.x);
            *(float4*)(dst + 1 * CB) = make_float4(v0.y, v1v.y, v2v.y, v3v.y);
            *(float4*)(dst + 2 * CB) = make_float4(v0.z, v1v.z, v2v.z, v3v.z);
            *(float4*)(dst + 3 * CB) = make_float4(v0.w, v1v.w, v2v.w, v3v.w);
        }
    }
    __syncthreads();

    // ---- PA: rs[pw][j][c8] = sum_i wx * patch (weights already in regs) ----
    if (a1) {
        const float* base = &patch[((size_t)j1r * ROWF + bi1) * CB + 4 * q1];
        float ax = 0.0f, ay = 0.0f, az = 0.0f, aw = 0.0f;
#pragma unroll
        for (int ii = 0; ii < 6; ++ii) {
            const float w = wxa[ii];
            const float4 v = *(const float4*)(base + ii * CB);
            ax += w * v.x; ay += w * v.y; az += w * v.z; aw += w * v.w;
        }
        *(float4*)(&rs[((size_t)pw1 * MAXJ + j1r) * CB + 4 * q1]) =
            make_float4(ax, ay, az, aw);
    }
    if (a2) {
        const float* base = &patch[((size_t)j2r * ROWF + bi2) * CB + 4 * q2];
        float ax = 0.0f, ay = 0.0f, az = 0.0f, aw = 0.0f;
#pragma unroll
        for (int ii = 0; ii < 6; ++ii) {
            const float w = wxb[ii];
            const float4 v = *(const float4*)(base + ii * CB);
            ax += w * v.x; ay += w * v.y; az += w * v.z; aw += w * v.w;
        }
        *(float4*)(&rs[((size_t)pw2 * MAXJ + j2r) * CB + 4 * q2]) =
            make_float4(ax, ay, az, aw);
    }
    __syncthreads();

    // ---- PB: combine over rows, float2 channel-pairs ----
    if (bin < NBINS) {
        const float* rbase = &rs[((size_t)pwv * MAXJ + bj) * CB + 2 * cp];
        float ax = 0.0f, ay = 0.0f;
#pragma unroll
        for (int jj = 0; jj < 6; ++jj) {
            const float w = wy[jj];
            const float2 v = *(const float2*)(rbase + jj * CB);
            ax += w * v.x; ay += w * v.y;
        }
        float* o = out + ((size_t)r * CH + c0 + 2 * cp) * NBINS + bin;
        o[0]     = ax * inv_area;
        o[NBINS] = ay * inv_area;
    }
}

extern "C" void kernel_launch(void* const* d_in, const int* in_sizes, int n_in,
                              void* d_out, int out_size, void* d_ws, size_t ws_size,
                              hipStream_t stream) {
    const float* feat = (const float*)d_in[0];
    const float* rois = (const float*)d_in[1];
    float* out = (float*)d_out;
    float* prm = (float*)d_ws;   // 300 * 112 * 4 = 134.4 KB

    prroi_prep<<<(RNUM + 3) / 4, 256, 0, stream>>>(rois, prm);
    prroi_main<<<dim3(CH / CB, RNUM), 256, 0, stream>>>(feat, prm, out);
}